// Round 3
// baseline (107.644 us; speedup 1.0000x reference)
//
#include <hip/hip_runtime.h>

// Fused MoE router + combine. B=4,S=4096,DIM=2048,BITS=32,HEXP=4 (f32).
// out[t,d] = x[t,d] * ( sum_e v[t,e]*aggr_w[e]*emb[idx[t,e],d] + aggr_b )
// (v,idx) = top4(softmax(x[t]@A1_w.T + A1_b)), descending, ties->lower idx.
//
// One block = 32 tokens, 512 threads (8 waves). Wave w owns dims
// [256w,256w+256) of the router GEMM (4x4 lane tile, LDS-staged 16-dim
// chunks, per-wave private buffers -> no barriers in the main loop).
// Then: LDS cross-wave logit reduction -> softmax/top4 (32 threads) ->
// gates in LDS -> combine phase re-reads x (L3-warm) and streams out.

#define NTOK 16384
#define DIMV 2048

__global__ __launch_bounds__(512, 4) void fused_moe(
    const float* __restrict__ x,
    const float* __restrict__ A1w,
    const float* __restrict__ A1b,
    const float* __restrict__ emb,
    const float* __restrict__ aggw,
    const float* __restrict__ aggb,
    float* __restrict__ out)
{
    __shared__ float smem[9216];      // 8 waves * (576 x + 576 w); reused as red[32][260]
    __shared__ float g_lds[256];      // 32 tokens * {4 gates, 4 idx-bits}

    const int tid  = threadIdx.x;
    const int wid  = tid >> 6;
    const int lane = tid & 63;
    const int tg   = lane & 7;        // token group: tokens 4tg..4tg+3
    const int kg   = lane >> 3;       // bit group:   bits  4kg..4kg+3
    const int tok0 = blockIdx.x << 5; // 32 tokens/block
    const int d0   = wid << 8;        // wave's 256-dim slice

    float* xs  = smem + wid * 1152;   // [32 rows][18]
    float* wsx = xs + 576;            // [32 rows][18]

    // staging map: 64 lanes cover 16 rows x 64B; two insts -> 32 rows
    const int srow = lane >> 2;       // 0..15
    const int scol = (lane & 3) << 2; // 0,4,8,12

    const float* xg0 = x   + (size_t)(tok0 + srow)      * DIMV + d0 + scol;
    const float* xg1 = x   + (size_t)(tok0 + srow + 16) * DIMV + d0 + scol;
    const float* wg0 = A1w + (size_t)(srow)             * DIMV + d0 + scol;
    const float* wg1 = A1w + (size_t)(srow + 16)        * DIMV + d0 + scol;

    float2 acc[4][4];
    #pragma unroll
    for (int i = 0; i < 4; ++i)
        #pragma unroll
        for (int j = 0; j < 4; ++j) acc[i][j] = make_float2(0.f, 0.f);

    // prefetch chunk 0
    float4 px0 = *(const float4*)(xg0);
    float4 px1 = *(const float4*)(xg1);
    float4 pw0 = *(const float4*)(wg0);
    float4 pw1 = *(const float4*)(wg1);

    for (int c = 0; c < 16; ++c) {    // 16 chunks x 16 dims = 256
        // stage current chunk (float2 pieces: pad-18 rows are 8B-aligned)
        {
            float* a = xs  + srow * 18 + scol;
            float* b = xs  + (srow + 16) * 18 + scol;
            float* d = wsx + srow * 18 + scol;
            float* e = wsx + (srow + 16) * 18 + scol;
            *(float2*)(a)     = make_float2(px0.x, px0.y);
            *(float2*)(a + 2) = make_float2(px0.z, px0.w);
            *(float2*)(b)     = make_float2(px1.x, px1.y);
            *(float2*)(b + 2) = make_float2(px1.z, px1.w);
            *(float2*)(d)     = make_float2(pw0.x, pw0.y);
            *(float2*)(d + 2) = make_float2(pw0.z, pw0.w);
            *(float2*)(e)     = make_float2(pw1.x, pw1.y);
            *(float2*)(e + 2) = make_float2(pw1.z, pw1.w);
        }
        // prefetch next chunk (wraps at end; harmless L1-hot re-load)
        {
            const int cn = (c + 1) & 15;
            px0 = *(const float4*)(xg0 + cn * 16);
            px1 = *(const float4*)(xg1 + cn * 16);
            pw0 = *(const float4*)(wg0 + cn * 16);
            pw1 = *(const float4*)(wg1 + cn * 16);
        }
        // compute: 8 d-pair steps, 4x4 register tile (same-wave DS ordering
        // makes LDS write->read safe without a barrier)
        #pragma unroll
        for (int dd = 0; dd < 16; dd += 2) {
            float2 xv[4], wv[4];
            #pragma unroll
            for (int i = 0; i < 4; ++i)
                xv[i] = *(const float2*)&xs[(4 * tg + i) * 18 + dd];
            #pragma unroll
            for (int j = 0; j < 4; ++j)
                wv[j] = *(const float2*)&wsx[(4 * kg + j) * 18 + dd];
            #pragma unroll
            for (int i = 0; i < 4; ++i)
                #pragma unroll
                for (int j = 0; j < 4; ++j) {
                    acc[i][j].x = fmaf(xv[i].x, wv[j].x, acc[i][j].x);
                    acc[i][j].y = fmaf(xv[i].y, wv[j].y, acc[i][j].y);
                }
        }
    }

    // cross-wave reduction: red[32 tokens][260] (32 k * 8 waves + 4 pad)
    __syncthreads();                  // all waves done with stage buffers
    float* red = smem;
    #pragma unroll
    for (int i = 0; i < 4; ++i)
        #pragma unroll
        for (int j = 0; j < 4; ++j)
            red[(4 * tg + i) * 260 + ((4 * kg + j) << 3) + wid] =
                acc[i][j].x + acc[i][j].y;
    __syncthreads();

    // softmax + top4 + gate precompute: one thread per token (32 of 512)
    if (tid < 32) {
        const int t = tid;
        float l[32];
        #pragma unroll
        for (int k = 0; k < 32; ++k) {
            float4 p0 = *(const float4*)&red[t * 260 + (k << 3)];
            float4 p1 = *(const float4*)&red[t * 260 + (k << 3) + 4];
            l[k] = ((p0.x + p0.y) + (p0.z + p0.w))
                 + ((p1.x + p1.y) + (p1.z + p1.w)) + A1b[k];
        }
        float m = l[0];
        #pragma unroll
        for (int k = 1; k < 32; ++k) m = fmaxf(m, l[k]);
        float s = 0.f;
        #pragma unroll
        for (int k = 0; k < 32; ++k) { l[k] = expf(l[k] - m); s += l[k]; }
        const float inv = 1.0f / s;

        unsigned used = 0u;
        #pragma unroll
        for (int e = 0; e < 4; ++e) {
            float best = -1.f; int bi = 0;
            #pragma unroll
            for (int k = 0; k < 32; ++k) {
                bool ok = !((used >> k) & 1u) && (l[k] > best);
                best = ok ? l[k] : best;
                bi   = ok ? k    : bi;
            }
            used |= (1u << bi);
            g_lds[t * 8 + e]     = best * inv * aggw[e];  // gate * aggr_w[e]
            g_lds[t * 8 + 4 + e] = __uint_as_float((unsigned)bi);
        }
    }
    __syncthreads();

    // combine + residual: 16 threads per token, x re-read is L3-warm
    const int tt  = tid >> 4;         // 0..31
    const int l16 = tid & 15;
    const float4 g = *(const float4*)&g_lds[tt * 8];
    const unsigned i0 = __float_as_uint(g_lds[tt * 8 + 4]);
    const unsigned i1 = __float_as_uint(g_lds[tt * 8 + 5]);
    const unsigned i2 = __float_as_uint(g_lds[tt * 8 + 6]);
    const unsigned i3 = __float_as_uint(g_lds[tt * 8 + 7]);
    const float bb = aggb[0];
    const size_t base = (size_t)(tok0 + tt) * DIMV;

    #pragma unroll 4
    for (int it = 0; it < 32; ++it) {
        const int d = (l16 << 2) + (it << 6);   // 16 lanes * 4 = 64 f32 / iter
        const float4 xv = *(const float4*)&x[base + d];
        const float4 e0 = *(const float4*)&emb[(size_t)i0 * DIMV + d];
        const float4 e1 = *(const float4*)&emb[(size_t)i1 * DIMV + d];
        const float4 e2 = *(const float4*)&emb[(size_t)i2 * DIMV + d];
        const float4 e3 = *(const float4*)&emb[(size_t)i3 * DIMV + d];
        float4 a, o;
        a.x = fmaf(g.x, e0.x, fmaf(g.y, e1.x, fmaf(g.z, e2.x, fmaf(g.w, e3.x, bb))));
        a.y = fmaf(g.x, e0.y, fmaf(g.y, e1.y, fmaf(g.z, e2.y, fmaf(g.w, e3.y, bb))));
        a.z = fmaf(g.x, e0.z, fmaf(g.y, e1.z, fmaf(g.z, e2.z, fmaf(g.w, e3.z, bb))));
        a.w = fmaf(g.x, e0.w, fmaf(g.y, e1.w, fmaf(g.z, e2.w, fmaf(g.w, e3.w, bb))));
        o.x = xv.x * a.x; o.y = xv.y * a.y; o.z = xv.z * a.z; o.w = xv.w * a.w;
        *(float4*)&out[base + d] = o;
    }
}

extern "C" void kernel_launch(void* const* d_in, const int* in_sizes, int n_in,
                              void* d_out, int out_size, void* d_ws, size_t ws_size,
                              hipStream_t stream)
{
    (void)in_sizes; (void)n_in; (void)out_size; (void)d_ws; (void)ws_size;
    const float* x    = (const float*)d_in[0];
    const float* A1w  = (const float*)d_in[1];
    const float* A1b  = (const float*)d_in[2];
    const float* emb  = (const float*)d_in[3];
    const float* aggw = (const float*)d_in[4];
    const float* aggb = (const float*)d_in[5];
    float* out = (float*)d_out;

    fused_moe<<<NTOK / 32, 512, 0, stream>>>(x, A1w, A1b, emb, aggw, aggb, out);
}